// Round 1
// baseline (93.916 us; speedup 1.0000x reference)
//
#include <hip/hip_runtime.h>
#include <stdint.h>

#define NROW 1024
#define DCOL 8192
#define T1   1024
#define EPT  8   // DCOL / T1

// order-preserving float -> uint32 transform
__device__ __forceinline__ uint32_t sortable_key(float f){
  uint32_t u = __float_as_uint(f);
  return u ^ ((uint32_t)((int32_t)u >> 31) | 0x80000000u);
}

// One block ranks one row (rows 0..1023 = pred, 1024..2047 = eeg).
// Exact rank = #{j: key[j] < key[i]} with key extended by index for tie-break,
// matching stable argsort-of-argsort.
extern "C" __global__ void __launch_bounds__(T1)
rank_kernel(const float* __restrict__ pred, const float* __restrict__ eeg,
            uint16_t* __restrict__ ranks)
{
  __shared__ uint32_t h[DCOL];     // 32 KB: hist1/counts, then hist2/prefix2
  __shared__ uint32_t ebuf[DCOL];  // 32 KB: p1 (u16, first 16KB) + wtot (tail), then scattered entries
  uint16_t* p1   = (uint16_t*)ebuf;        // ebuf[0..4095] as 8192 u16
  uint32_t* wtot = ebuf + DCOL - 16;       // ebuf[8176..8191]

  const int t = threadIdx.x;
  const int r = blockIdx.x;
  const float* src = (r < NROW) ? pred + (size_t)r * DCOL
                                : eeg  + (size_t)(r - NROW) * DCOL;

  // load 8 contiguous floats (two float4), make sortable keys
  uint32_t key[EPT];
  {
    const float4* s4 = (const float4*)(src + t * EPT);
    float4 a = s4[0], b = s4[1];
    key[0]=sortable_key(a.x); key[1]=sortable_key(a.y);
    key[2]=sortable_key(a.z); key[3]=sortable_key(a.w);
    key[4]=sortable_key(b.x); key[5]=sortable_key(b.y);
    key[6]=sortable_key(b.z); key[7]=sortable_key(b.w);
  }

  // ---- pass 1: histogram of top 13 bits ----
  #pragma unroll
  for (int j=0;j<EPT;j++) h[t*EPT+j] = 0;
  __syncthreads();
  #pragma unroll
  for (int j=0;j<EPT;j++) atomicAdd(&h[key[j]>>19], 1u);
  __syncthreads();

  // scan1: p1 = exclusive prefix of h; h keeps the counts
  {
    uint32_t c[EPT]; uint32_t tot=0;
    #pragma unroll
    for (int j=0;j<EPT;j++){ c[j]=h[t*EPT+j]; tot+=c[j]; }
    uint32_t v=tot; int lane=t&63, wid=t>>6;
    #pragma unroll
    for (int o=1;o<64;o<<=1){ uint32_t u=__shfl_up(v,o,64); if(lane>=o) v+=u; }
    if (lane==63) wtot[wid]=v;
    __syncthreads();
    uint32_t woff=0;
    for (int w=0;w<wid;w++) woff += wtot[w];
    uint32_t run = woff + v - tot;   // exclusive prefix of this thread's first bin
    #pragma unroll
    for (int j=0;j<EPT;j++){ p1[t*EPT+j]=(uint16_t)run; run+=c[j]; }
  }
  __syncthreads();

  // refined bucket: b2 = P1[hi] + floor(lo19 * cnt / 2^19)  (monotone, disjoint ranges)
  uint32_t b2[EPT];
  #pragma unroll
  for (int j=0;j<EPT;j++){
    uint32_t hi = key[j]>>19, lo = key[j]&0x7FFFFu;
    uint32_t cnt = h[hi];                       // <= 8192; lo*cnt < 2^32
    b2[j] = (uint32_t)p1[hi] + ((lo*cnt)>>19);
  }
  __syncthreads();

  // ---- pass 2: histogram of refined buckets ----
  #pragma unroll
  for (int j=0;j<EPT;j++) h[t*EPT+j]=0;
  __syncthreads();
  #pragma unroll
  for (int j=0;j<EPT;j++) atomicAdd(&h[b2[j]],1u);
  __syncthreads();

  // scan2: h -> exclusive prefix, in place (each thread touches only its own bins)
  {
    uint32_t c[EPT]; uint32_t tot=0;
    #pragma unroll
    for (int j=0;j<EPT;j++){ c[j]=h[t*EPT+j]; tot+=c[j]; }
    uint32_t v=tot; int lane=t&63, wid=t>>6;
    #pragma unroll
    for (int o=1;o<64;o<<=1){ uint32_t u=__shfl_up(v,o,64); if(lane>=o) v+=u; }
    if (lane==63) wtot[wid]=v;
    __syncthreads();
    uint32_t woff=0;
    for (int w=0;w<wid;w++) woff += wtot[w];
    uint32_t run = woff + v - tot;
    #pragma unroll
    for (int j=0;j<EPT;j++){ h[t*EPT+j]=run; run+=c[j]; }
  }
  __syncthreads();

  // bucket starts (must be read before scatter atomics mutate h)
  uint32_t st[EPT];
  #pragma unroll
  for (int j=0;j<EPT;j++) st[j] = h[b2[j]];
  __syncthreads();

  // scatter (lo19,idx13) entries; h[b] advances to bucket end
  uint32_t e[EPT];
  #pragma unroll
  for (int j=0;j<EPT;j++){
    e[j] = ((key[j]&0x7FFFFu)<<13) | (uint32_t)(t*EPT+j);
    uint32_t pos = atomicAdd(&h[b2[j]],1u);
    ebuf[pos] = e[j];
  }
  __syncthreads();

  // exact rank = start + #(smaller entries in my refined bucket)
  uint32_t rk[EPT];
  #pragma unroll
  for (int j=0;j<EPT;j++){
    uint32_t en = h[b2[j]];     // end
    uint32_t cnt=0;
    for (uint32_t p=st[j]; p<en; ++p) cnt += (ebuf[p] < e[j]) ? 1u : 0u;
    rk[j] = st[j]+cnt;
  }
  uint4 pack;
  pack.x = rk[0] | (rk[1]<<16);
  pack.y = rk[2] | (rk[3]<<16);
  pack.z = rk[4] | (rk[5]<<16);
  pack.w = rk[6] | (rk[7]<<16);
  *(uint4*)(ranks + (size_t)r*DCOL + (size_t)t*EPT) = pack;
}

// Column sums SA/SB (u32 atomics, exact) + total diag dot sum (u64 atomic, exact)
extern "C" __global__ void __launch_bounds__(256)
colstats_kernel(const uint16_t* __restrict__ ranks,
                uint32_t* __restrict__ SA, uint32_t* __restrict__ SB,
                unsigned long long* __restrict__ dotacc)
{
  __shared__ unsigned long long wpart[4];
  const int t = threadIdx.x;
  const int k = blockIdx.x*256 + t;
  const int r0 = blockIdx.y*128;
  const uint16_t* rp = ranks;
  const uint16_t* re = ranks + (size_t)NROW*DCOL;
  uint32_t sa=0, sb=0; unsigned long long dt=0;
  for (int i=0;i<128;i++){
    uint32_t a = rp[(size_t)(r0+i)*DCOL + k];
    uint32_t b = re[(size_t)(r0+i)*DCOL + k];
    sa += a; sb += b;
    dt += (unsigned long long)(a*b);   // a*b <= 8191^2 fits u32
  }
  atomicAdd(&SA[k], sa);
  atomicAdd(&SB[k], sb);
  for (int o=32;o>0;o>>=1) dt += __shfl_down(dt,o,64);
  int lane=t&63, wid=t>>6;
  if (lane==0) wpart[wid]=dt;
  __syncthreads();
  if (t==0) atomicAdd(dotacc, wpart[0]+wpart[1]+wpart[2]+wpart[3]);
}

extern "C" __global__ void __launch_bounds__(256)
mse_kernel(const float* __restrict__ pred, const float* __restrict__ eeg,
           double* __restrict__ partials)
{
  __shared__ double wpartd[4];
  const size_t total = (size_t)NROW*DCOL;              // 8388608
  size_t idx    = ((size_t)blockIdx.x*256 + threadIdx.x)*4;
  size_t stride = (size_t)gridDim.x*256*4;
  double s=0.0;
  for (size_t i=idx; i<total; i+=stride){
    float4 p = *(const float4*)(pred+i);
    float4 e = *(const float4*)(eeg+i);
    float d0=p.x-e.x, d1=p.y-e.y, d2=p.z-e.z, d3=p.w-e.w;
    s += (double)(d0*d0)+(double)(d1*d1)+(double)(d2*d2)+(double)(d3*d3);
  }
  for (int o=32;o>0;o>>=1) s += __shfl_down(s,o,64);
  int lane=threadIdx.x&63, wid=threadIdx.x>>6;
  if (lane==0) wpartd[wid]=s;
  __syncthreads();
  if (threadIdx.x==0) partials[blockIdx.x]=wpartd[0]+wpartd[1]+wpartd[2]+wpartd[3];
}

extern "C" __global__ void __launch_bounds__(256)
final_kernel(const uint32_t* __restrict__ SA, const uint32_t* __restrict__ SB,
             const unsigned long long* __restrict__ dotacc,
             const double* __restrict__ msepart, int nmse,
             float* __restrict__ out)
{
  __shared__ double wpartd[4];
  __shared__ double wpartm[4];
  const int t = threadIdx.x;
  const double NMU = 4193792.0;    // N * mu, mu = (D-1)/2 = 4095.5
  double s = 0.0;
  for (int i=0;i<DCOL/256;i++){
    int k = i*256+t;
    s += ((double)SA[k]-NMU)*((double)SB[k]-NMU);
  }
  double m = 0.0;
  for (int i=t; i<nmse; i+=256) m += msepart[i];
  for (int o=32;o>0;o>>=1){ s+=__shfl_down(s,o,64); m+=__shfl_down(m,o,64); }
  int lane=t&63, wid=t>>6;
  if (lane==0){ wpartd[wid]=s; wpartm[wid]=m; }
  __syncthreads();
  if (t==0){
    double sasb   = wpartd[0]+wpartd[1]+wpartd[2]+wpartd[3];
    double msesum = wpartm[0]+wpartm[1]+wpartm[2]+wpartm[3];
    const double C     = 45812983808.0;        // D*(D^2-1)/12
    const double NDMU2 = 140703130714112.0;    // N * D * mu^2
    double dot = (double)(*dotacc);
    double diag_sum = (dot - NDMU2) / C;       // sum_i corr_ii
    double pos = diag_sum / (double)NROW;
    double stotal = sasb / C;                  // sum_ij corr_ij
    double neg = (stotal - diag_sum) / ((double)NROW*(double)(NROW-1));
    double loss1 = msesum / ((double)NROW*(double)DCOL);
    out[0] = (float)(loss1 + 1.0 - pos + neg);
  }
}

extern "C" void kernel_launch(void* const* d_in, const int* in_sizes, int n_in,
                              void* d_out, int out_size, void* d_ws, size_t ws_size,
                              hipStream_t stream)
{
  const float* pred = (const float*)d_in[0];
  const float* eeg  = (const float*)d_in[1];
  float* out = (float*)d_out;

  char* ws = (char*)d_ws;
  const size_t OFF_ACC = (size_t)2*NROW*DCOL*sizeof(uint16_t);   // 33,554,432
  const size_t NEED = OFF_ACC + 65536 + 64 + 1024*sizeof(double);
  if (ws_size < NEED){
    // signal: ws too small -> NaN output (distinguishable from wrong math)
    hipMemsetAsync(d_out, 0xFF, sizeof(float), stream);
    return;
  }
  uint16_t* ranks = (uint16_t*)ws;
  uint32_t* SA = (uint32_t*)(ws + OFF_ACC);
  uint32_t* SB = (uint32_t*)(ws + OFF_ACC + 32768);
  unsigned long long* dotacc = (unsigned long long*)(ws + OFF_ACC + 65536);
  double* msepart = (double*)(ws + OFF_ACC + 65536 + 64);

  hipMemsetAsync(ws + OFF_ACC, 0, 65536 + 64, stream);   // zero SA, SB, dotacc

  rank_kernel<<<dim3(2*NROW), dim3(T1), 0, stream>>>(pred, eeg, ranks);
  colstats_kernel<<<dim3(DCOL/256, 8), dim3(256), 0, stream>>>(ranks, SA, SB, dotacc);
  mse_kernel<<<dim3(1024), dim3(256), 0, stream>>>(pred, eeg, msepart);
  final_kernel<<<dim3(1), dim3(256), 0, stream>>>(SA, SB, dotacc, msepart, 1024, out);
}